// Round 9
// baseline (277.711 us; speedup 1.0000x reference)
//
#include <hip/hip_runtime.h>
#include <math.h>

#define NN 16384
#define NP 8192
#define NL 8192
#define KW 32
#define VC 100000
#define NSWEEP 8
#define REVW 8
#define CLEAN_EPOCH 1000

__device__ __forceinline__ float sigmoidf_(float x){ return 1.0f/(1.0f+expf(-x)); }

// ---- K1: fused setup: E-transpose + 6 weight transposes + scheduling state ----
// rcnt/fcnt pre-zeroed by hipMemsetAsync.
__global__ void __launch_bounds__(256) k_setup(const float* __restrict__ E, float* __restrict__ ET,
    const float* __restrict__ Wz, const float* __restrict__ Wr, const float* __restrict__ Wh,
    const float* __restrict__ Uz, const float* __restrict__ Ur, const float* __restrict__ Uh,
    float* __restrict__ WT, const int* __restrict__ tree,
    int* pending, int* npc, int* done, int* rcnt, int* rev, int* fcnt, int* fr0, int* g_rem,
    int et_blocks){
  __shared__ float tile[64][65];
  int b = blockIdx.x;
  int lane = threadIdx.x & 63, ty = threadIdx.x >> 6;
  if (b < et_blocks){
    int v0 = b*64;
    for (int h = ty; h < 64; h += 4){
      int v = v0 + lane;
      tile[h][lane] = (v < VC) ? E[(size_t)h*VC + v] : 0.f;
    }
    __syncthreads();
    for (int vv = ty; vv < 64; vv += 4){
      int v = v0 + vv;
      if (v < VC) ET[v*64 + lane] = tile[lane][vv];
    }
  } else if (b < et_blocks + 6){
    int m = b - et_blocks;
    const float* src = (m==0)?Wz:(m==1)?Wr:(m==2)?Wh:(m==3)?Uz:(m==4)?Ur:Uh;
    float* dst = WT + m*4096;
    for (int h = ty; h < 64; h += 4) tile[h][lane] = src[h*64 + lane];
    __syncthreads();
    for (int k = ty; k < 64; k += 4) dst[k*64 + lane] = tile[lane][k];
  } else {
    int idx = (b - et_blocks - 6)*256 + threadIdx.x;   // one thread per parent
    if (idx < NP){
      const int* tr = tree + idx*5;
      int cnt = 0;
      #pragma unroll
      for (int j=0;j<4;++j){
        int c = tr[j];
        if (c >= NL){
          ++cnt;
          int cc = c - NL;
          int slot = atomicAdd(&rcnt[cc], 1);
          if (slot < REVW) rev[cc*REVW + slot] = idx;   // overflow -> cleanup backstop
        }
      }
      pending[idx] = cnt;
      npc[idx] = cnt;
      done[idx] = 0;
      if (cnt == 0){ int pos = atomicAdd(&fcnt[0], 1); fr0[pos] = idx; }
      if (idx == 0) *g_rem = NP;
    }
  }
}

// -------- shared node-transform body (leaf GRU + parent precompute) --------
__device__ __forceinline__ void node_body(int wid, int lane, float xev,
    const float* __restrict__ WzT, const float* __restrict__ WrT,
    const float* __restrict__ WhT, const float* __restrict__ Wa,
    const float* __restrict__ bz, const float* __restrict__ br,
    const float* __restrict__ bh,
    float* __restrict__ node_h, float* __restrict__ pz, float* __restrict__ pr,
    float* __restrict__ pc, float* __restrict__ qa){
  if (wid < NL){
    float az0=0.f, az1=0.f, ah0=0.f, ah1=0.f;
    #pragma unroll 8
    for (int k=0;k<64;k+=2){
      float x0 = __shfl(xev, k), x1 = __shfl(xev, k+1);
      az0 += x0 * WzT[k*64+lane];     az1 += x1 * WzT[(k+1)*64+lane];
      ah0 += x0 * WhT[k*64+lane];     ah1 += x1 * WhT[(k+1)*64+lane];
    }
    float z = sigmoidf_(az0+az1 + bz[lane]);
    float c = tanhf(ah0+ah1 + bh[lane]);
    node_h[wid*64+lane] = (1.f-z)*c;
  } else {
    int i = wid - NL;
    float az=0.f, ar=0.f, ah=0.f, aq=0.f;
    #pragma unroll 4
    for (int k=0;k<64;++k){
      float xk = __shfl(xev, k);
      az += xk * WzT[k*64+lane];
      ar += xk * WrT[k*64+lane];
      ah += xk * WhT[k*64+lane];
      aq += xk * Wa [k*64+lane];
    }
    pz[i*64+lane] = az + bz[lane];
    pr[i*64+lane] = ar + br[lane];
    pc[i*64+lane] = ah + bh[lane];
    qa[i*64+lane] = aq;
  }
}

// ---- K2: FUSED xe-gather + node transform (one wave per node) ----
__global__ void __launch_bounds__(256) k_xenode(const float* __restrict__ xw,
    const int* __restrict__ xi, const float* __restrict__ ET,
    const float* __restrict__ WzT, const float* __restrict__ WrT,
    const float* __restrict__ WhT, const float* __restrict__ Wa,
    const float* __restrict__ bz, const float* __restrict__ br,
    const float* __restrict__ bh,
    float* __restrict__ node_h, float* __restrict__ pz, float* __restrict__ pr,
    float* __restrict__ pc, float* __restrict__ qa){
  int wid = blockIdx.x*(blockDim.x>>6) + (threadIdx.x>>6);
  int lane = threadIdx.x & 63;
  if (wid >= NN) return;
  int   idxl = (lane < KW) ? xi[wid*KW + lane] : 0;
  float wl   = (lane < KW) ? xw[wid*KW + lane] : 0.f;
  float xev = 0.f;
  #pragma unroll 8
  for (int k = 0; k < KW; ++k){
    int   vk = __shfl(idxl, k);
    float wk = __shfl(wl,   k);
    xev += wk * ET[vk*64 + lane];
  }
  node_body(wid, lane, xev, WzT,WrT,WhT,Wa, bz,br,bh, node_h, pz,pr,pc, qa);
}

// K2b fallback: strided gather from E (only if ws too small for ET)
__global__ void __launch_bounds__(256) k_xenode_direct(const float* __restrict__ xw,
    const int* __restrict__ xi, const float* __restrict__ E,
    const float* __restrict__ WzT, const float* __restrict__ WrT,
    const float* __restrict__ WhT, const float* __restrict__ Wa,
    const float* __restrict__ bz, const float* __restrict__ br,
    const float* __restrict__ bh,
    float* __restrict__ node_h, float* __restrict__ pz, float* __restrict__ pr,
    float* __restrict__ pc, float* __restrict__ qa){
  int wid = blockIdx.x*(blockDim.x>>6) + (threadIdx.x>>6);
  int lane = threadIdx.x & 63;
  if (wid >= NN) return;
  const float* w = xw + wid*KW;
  const int*   v = xi + wid*KW;
  const float* Erow = E + (size_t)lane*VC;
  float xev = 0.f;
  for (int k = 0; k < KW; ++k) xev += w[k] * Erow[v[k]];
  node_body(wid, lane, xev, WzT,WrT,WhT,Wa, bz,br,bh, node_h, pz,pr,pc, qa);
}

// ---------------- shared per-parent GRU step (no LDS, split chains) ----------------
__device__ __forceinline__ void gru_parent(int i, int lane,
    int c0,int c1,int c2,int c3,
    const float* __restrict__ qa, const float* __restrict__ pz,
    const float* __restrict__ pr, const float* __restrict__ pc,
    const float* __restrict__ UzT, const float* __restrict__ UrT,
    const float* __restrict__ UhT, float* node_h)
{
  float chv0 = (c0>=0)? node_h[c0*64+lane] : 0.f;
  float chv1 = (c1>=0)? node_h[c1*64+lane] : 0.f;
  float chv2 = (c2>=0)? node_h[c2*64+lane] : 0.f;
  float chv3 = (c3>=0)? node_h[c3*64+lane] : 0.f;
  float q = qa[i*64+lane];
  float d0=q*chv0, d1=q*chv1, d2=q*chv2, d3=q*chv3;
  #pragma unroll
  for (int off=32; off; off>>=1){
    d0 += __shfl_xor(d0, off); d1 += __shfl_xor(d1, off);
    d2 += __shfl_xor(d2, off); d3 += __shfl_xor(d3, off);
  }
  float l0 = (c0>=0)? sigmoidf_(d0) : -1e30f;
  float l1 = (c1>=0)? sigmoidf_(d1) : -1e30f;
  float l2 = (c2>=0)? sigmoidf_(d2) : -1e30f;
  float l3 = (c3>=0)? sigmoidf_(d3) : -1e30f;
  float mx = fmaxf(fmaxf(l0,l1), fmaxf(l2,l3));
  float e0=expf(l0-mx), e1=expf(l1-mx), e2=expf(l2-mx), e3=expf(l3-mx);
  float inv = 1.f/(e0+e1+e2+e3);
  float ht = (e0*chv0 + e1*chv1 + e2*chv2 + e3*chv3)*inv;   // h_tilde[lane]
  float az0=0.f, az1=0.f, ar0=0.f, ar1=0.f;
  #pragma unroll 8
  for (int k=0;k<64;k+=2){
    float h0 = __shfl(ht, k), h1 = __shfl(ht, k+1);
    az0 += h0 * UzT[k*64+lane];     az1 += h1 * UzT[(k+1)*64+lane];
    ar0 += h0 * UrT[k*64+lane];     ar1 += h1 * UrT[(k+1)*64+lane];
  }
  float z = sigmoidf_(pz[i*64+lane] + az0+az1);
  float r = sigmoidf_(pr[i*64+lane] + ar0+ar1);
  float rh = r*ht;
  float ac0=0.f, ac1=0.f, ac2=0.f, ac3=0.f;
  #pragma unroll 8
  for (int k=0;k<64;k+=4){
    float r0 = __shfl(rh, k),   r1 = __shfl(rh, k+1);
    float r2 = __shfl(rh, k+2), r3 = __shfl(rh, k+3);
    ac0 += r0 * UhT[k*64+lane];     ac1 += r1 * UhT[(k+1)*64+lane];
    ac2 += r2 * UhT[(k+2)*64+lane]; ac3 += r3 * UhT[(k+3)*64+lane];
  }
  float cc = tanhf(pc[i*64+lane] + (ac0+ac1)+(ac2+ac3));
  node_h[(NL+i)*64+lane] = z*ht + (1.f-z)*cc;
}

__device__ __forceinline__ bool lvl_ready(int c, int lvl, const int* done){
  if (c < NL) return true;
  int e = done[c - NL];
  return (e > 0 && e < lvl);
}

// ---- K3: frontier sweep with in-dispatch CHAIN COMPRESSION ----
// Frontier entries were enqueued in an earlier dispatch -> children visible.
// After completing parent i, if a consumer's pending hits 0 and it has exactly
// ONE parent-child (npc==1, namely i itself), the SAME wave processes it now:
// the only intra-dispatch dependency is this wave's own just-written node_h row
// (same-thread RAW). Other ready consumers defer to the next dispatch (safe).
__global__ void __launch_bounds__(256) k_front(const int* __restrict__ tree,
    const float* __restrict__ qa, const float* __restrict__ pz,
    const float* __restrict__ pr, const float* __restrict__ pc,
    const float* __restrict__ UzT, const float* __restrict__ UrT,
    const float* __restrict__ UhT,
    float* node_h, int* done, int* g_rem,
    int* pending, const int* __restrict__ npc,
    const int* __restrict__ rcnt, const int* __restrict__ rev,
    int* fcnt, const int* __restrict__ frIn, int* frOut, int s)
{
  int cnt = fcnt[s];
  int w = threadIdx.x >> 6, lane = threadIdx.x & 63;
  int nwaves = gridDim.x*4;
  for (int wid = blockIdx.x*4 + w; wid < cnt; wid += nwaves){
    int i = frIn[wid];
    while (i >= 0){
      const int* tr = tree + i*5;
      gru_parent(i, lane, tr[0],tr[1],tr[2],tr[3], qa,pz,pr,pc, UzT,UrT,UhT, node_h);
      int next = -1;
      if (lane == 0){
        done[i] = s + 1;
        atomicAdd(g_rem, -1);
        int rc = rcnt[i]; if (rc > REVW) rc = REVW;
        for (int j = 0; j < rc; ++j){
          int cons = rev[i*REVW + j];
          if (atomicSub(&pending[cons], 1) == 1){     // we complete its last parent-child
            if (npc[cons] == 1 && next < 0) next = cons;   // chain: its only parent-child is i
            else { int pos = atomicAdd(&fcnt[s+1], 1); frOut[pos] = cons; }
          }
        }
      }
      i = __shfl(next, 0);
    }
  }
}

// ------------- K4: single-block cleanup (guaranteed termination, proven) -------------
__global__ void __launch_bounds__(256) k_cleanup(const int* __restrict__ tree,
    const float* __restrict__ qa, const float* __restrict__ pz,
    const float* __restrict__ pr, const float* __restrict__ pc,
    const float* __restrict__ UzT, const float* __restrict__ UrT,
    const float* __restrict__ UhT,
    float* node_h, int* done, int* g_rem)
{
  int rem = *g_rem;
  if (rem <= 0) return;
  __shared__ int cnt_s;
  int w = threadIdx.x >> 6, lane = threadIdx.x & 63;
  int epoch = CLEAN_EPOCH;
  while (rem > 0){
    if (threadIdx.x == 0) cnt_s = 0;
    __syncthreads();
    int my = 0;
    for (int i = w; i < NP; i += 4){
      if (done[i]) continue;
      const int* tr = tree + i*5;
      int c0=tr[0], c1=tr[1], c2=tr[2], c3=tr[3];
      if (!(lvl_ready(c0,epoch,done) && lvl_ready(c1,epoch,done)
         && lvl_ready(c2,epoch,done) && lvl_ready(c3,epoch,done))) continue;
      gru_parent(i, lane, c0,c1,c2,c3, qa,pz,pr,pc, UzT,UrT,UhT, node_h);
      if (lane==0) done[i] = epoch;
      ++my;
    }
    if (lane==0 && my) atomicAdd(&cnt_s, my);
    __syncthreads();
    rem -= cnt_s;
    ++epoch;
    __syncthreads();
  }
}

// ---------------- K5a/K5b: max-pool + head ----------------
__global__ void k_max1(const float* __restrict__ node_h, float* __restrict__ partial){
  __shared__ float sm[4][64];
  int lane = threadIdx.x & 63, w = threadIdx.x>>6;
  int base = NL + blockIdx.x*128;
  float m = -1e30f;
  for (int r = w; r < 128; r += 4)
    m = fmaxf(m, node_h[(size_t)(base+r)*64 + lane]);
  sm[w][lane] = m;
  __syncthreads();
  if (w==0){
    m = fmaxf(fmaxf(sm[0][lane],sm[1][lane]), fmaxf(sm[2][lane],sm[3][lane]));
    partial[blockIdx.x*64+lane] = m;
  }
}

__global__ void k_max2(const float* __restrict__ partial, const float* __restrict__ Wout,
                       const float* __restrict__ bout, float* __restrict__ out){
  int lane = threadIdx.x;   // 64 threads = 1 wave
  float m = -1e30f;
  for (int b=0;b<64;++b) m = fmaxf(m, partial[b*64+lane]);
  float s0 = Wout[0*64+lane]*m;
  float s1 = Wout[1*64+lane]*m;
  float s2 = Wout[2*64+lane]*m;
  float s3 = Wout[3*64+lane]*m;
  #pragma unroll
  for (int off=32; off; off>>=1){
    s0 += __shfl_xor(s0, off);
    s1 += __shfl_xor(s1, off);
    s2 += __shfl_xor(s2, off);
    s3 += __shfl_xor(s3, off);
  }
  s0 += bout[0]; s1 += bout[1]; s2 += bout[2]; s3 += bout[3];
  float mx = fmaxf(fmaxf(s0,s1), fmaxf(s2,s3));
  float e0=expf(s0-mx), e1=expf(s1-mx), e2=expf(s2-mx), e3=expf(s3-mx);
  float inv = 1.f/(e0+e1+e2+e3);
  if (lane==0){
    out[0]=e0*inv; out[1]=e1*inv; out[2]=e2*inv; out[3]=e3*inv;
  }
}

__global__ void k_ws_sentinel(float* out, float wsmb){
  if (threadIdx.x < 4) out[threadIdx.x] = wsmb;
}

extern "C" void kernel_launch(void* const* d_in, const int* in_sizes, int n_in,
                              void* d_out, int out_size, void* d_ws, size_t ws_size,
                              hipStream_t stream){
  const float* x_word = (const float*)d_in[0];
  const int*   x_index= (const int*)d_in[1];
  const int*   tree   = (const int*)d_in[2];
  const float* E      = (const float*)d_in[3];
  const float* Wz     = (const float*)d_in[4];
  const float* Uz     = (const float*)d_in[5];
  const float* bz     = (const float*)d_in[6];
  const float* Wr     = (const float*)d_in[7];
  const float* Ur     = (const float*)d_in[8];
  const float* br     = (const float*)d_in[9];
  const float* Wh     = (const float*)d_in[10];
  const float* Uh     = (const float*)d_in[11];
  const float* bh     = (const float*)d_in[12];
  const float* Wa     = (const float*)d_in[13];
  const float* Wout   = (const float*)d_in[14];
  const float* bout   = (const float*)d_in[15];
  float* out = (float*)d_out;

  float* ws = (float*)d_ws;

  // region0: ET (6,400,000 f) during {setup, xenode}. After k_xenode ET is dead and
  // region0 is reused for qa/pz/pr/pc (2,097,152) + part (4,096) + nodeh (1,048,576)
  //   -- NOTE: nodeh IS written by k_xenode... so nodeh must NOT alias ET. Keep nodeh
  //   in the tail. Layout below reflects that.
  const size_t R0_FULL = 6400000;            // ET  (aliases qa..pc+part after k_xenode?  NO --
                                             // qa/pz/pr/pc are ALSO written by k_xenode.)
  // => everything written by k_xenode must be outside ET. Only part (4,096 f) aliases ET.
  const size_t TAIL = (size_t)2097152 /*qa..pc*/ + 1048576 /*nodeh*/ + 24576 /*WT*/
                    + (NP + 1 + NP + NP + NP + 16 + NP + NP + NP*REVW); // done,g_rem,pending,npc,rcnt,fcnt,fr0,fr1,rev
  const size_t FULL_NEED = (R0_FULL + TAIL) * 4;   // ~26.7 MB (< proven-available 28.9 MB)
  const size_t FB_NEED   = (4096 + TAIL) * 4;      // ~13.2 MB

  bool full = (ws_size >= FULL_NEED);
  bool fb   = (!full && ws_size >= FB_NEED);
  if (!full && !fb){
    k_ws_sentinel<<<1, 64, 0, stream>>>(out, (float)(ws_size >> 20));
    return;
  }

  float* ET   = ws;                          // full path only; dead after k_xenode
  float* part = ws;                          // aliases ET start; written only by k_max1
  size_t r0   = full ? R0_FULL : (size_t)4096;
  float* qa    = ws + r0;                    // 4 x 524,288
  float* pz    = qa + 524288;
  float* pr    = pz + 524288;
  float* pc    = pr + 524288;
  float* nodeh = pc + 524288;                // 1,048,576 f
  float* WT    = nodeh + 1048576;            // 24,576 f
  int*   done    = (int*)(WT + 24576);       // NP
  int*   g_rem   = done + NP;                // 1
  int*   pending = g_rem + 1;                // NP
  int*   npc     = pending + NP;             // NP
  int*   rcnt    = npc + NP;                 // NP
  int*   fcnt    = rcnt + NP;                // 16  (contiguous with rcnt for one memset)
  int*   fr0     = fcnt + 16;                // NP
  int*   fr1     = fr0 + NP;                 // NP
  int*   rev     = fr1 + NP;                 // NP*REVW
  float* WzT = WT,       *WrT = WT+4096,  *WhT = WT+8192;
  float* UzT = WT+12288, *UrT = WT+16384, *UhT = WT+20480;

  hipMemsetAsync(rcnt, 0, (NP + 16)*sizeof(int), stream);

  int et_blocks = full ? (VC+63)/64 : 0;     // 1563 or 0
  k_setup<<<et_blocks + 6 + NP/256, 256, 0, stream>>>(E, ET, Wz, Wr, Wh, Uz, Ur, Uh,
                                                      WT, tree, pending, npc, done, rcnt,
                                                      rev, fcnt, fr0, g_rem, et_blocks);
  if (full)
    k_xenode<<<NN/4, 256, 0, stream>>>(x_word, x_index, ET, WzT, WrT, WhT, Wa,
                                       bz, br, bh, nodeh, pz, pr, pc, qa);
  else
    k_xenode_direct<<<NN/4, 256, 0, stream>>>(x_word, x_index, E, WzT, WrT, WhT, Wa,
                                              bz, br, bh, nodeh, pz, pr, pc, qa);

  static const int fblocks[NSWEEP] = {2048, 1024, 512, 256, 128, 64, 64, 64};
  for (int s = 0; s < NSWEEP; ++s){
    const int* frIn  = (s & 1) ? fr1 : fr0;
    int*       frOut = (s & 1) ? fr0 : fr1;
    k_front<<<fblocks[s], 256, 0, stream>>>(tree, qa, pz, pr, pc, UzT, UrT, UhT,
                                            nodeh, done, g_rem, pending, npc, rcnt, rev,
                                            fcnt, frIn, frOut, s);
  }
  k_cleanup<<<1,  256, 0, stream>>>(tree, qa, pz, pr, pc, UzT, UrT, UhT,
                                    nodeh, done, g_rem);
  k_max1   <<<64, 256, 0, stream>>>(nodeh, part);
  k_max2   <<<1,   64, 0, stream>>>(part, Wout, bout, out);
}

// Round 10
// 202.484 us; speedup vs baseline: 1.3715x; 1.3715x over previous
//
#include <hip/hip_runtime.h>
#include <math.h>

#define NN 16384
#define NP 8192
#define NL 8192
#define KW 32
#define VC 100000
#define SENT 0xFFFFFFFFu
#define CLEAN_EPOCH 1000

__device__ __forceinline__ float sigmoidf_(float x){ return 1.0f/(1.0f+expf(-x)); }

// ---- K1: fused setup: E-transpose + 6 weight transposes + done/g_rem init ----
__global__ void __launch_bounds__(256) k_setup(const float* __restrict__ E, float* __restrict__ ET,
    const float* __restrict__ Wz, const float* __restrict__ Wr, const float* __restrict__ Wh,
    const float* __restrict__ Uz, const float* __restrict__ Ur, const float* __restrict__ Uh,
    float* __restrict__ WT, int* done, int* g_rem, int et_blocks){
  __shared__ float tile[64][65];
  int b = blockIdx.x;
  int lane = threadIdx.x & 63, ty = threadIdx.x >> 6;
  if (b < et_blocks){
    int v0 = b*64;
    for (int h = ty; h < 64; h += 4){
      int v = v0 + lane;
      tile[h][lane] = (v < VC) ? E[(size_t)h*VC + v] : 0.f;
    }
    __syncthreads();
    for (int vv = ty; vv < 64; vv += 4){
      int v = v0 + vv;
      if (v < VC) ET[v*64 + lane] = tile[lane][vv];
    }
  } else if (b < et_blocks + 6){
    int m = b - et_blocks;
    const float* src = (m==0)?Wz:(m==1)?Wr:(m==2)?Wh:(m==3)?Uz:(m==4)?Ur:Uh;
    float* dst = WT + m*4096;
    for (int h = ty; h < 64; h += 4) tile[h][lane] = src[h*64 + lane];
    __syncthreads();
    for (int k = ty; k < 64; k += 4) dst[k*64 + lane] = tile[lane][k];
  } else {
    int idx = (b - et_blocks - 6)*256 + threadIdx.x;
    if (idx < NP) done[idx] = 0;
    if (idx == 0) *g_rem = NP;
  }
}

// ---------------- K2a: xe = einsum over gathered ET rows ----------------
__global__ void k_xe(const float* __restrict__ xw, const int* __restrict__ xi,
                     const float* __restrict__ ET, float* __restrict__ xe){
  int wid = blockIdx.x*(blockDim.x>>6) + (threadIdx.x>>6);
  int lane = threadIdx.x & 63;
  if (wid >= NN) return;
  int   idxl = (lane < KW) ? xi[wid*KW + lane] : 0;
  float wl   = (lane < KW) ? xw[wid*KW + lane] : 0.f;
  float acc = 0.f;
  #pragma unroll 8
  for (int k = 0; k < KW; ++k){
    int   vk = __shfl(idxl, k);
    float wk = __shfl(wl,   k);
    acc += wk * ET[vk*64 + lane];
  }
  xe[wid*64 + lane] = acc;
}

// K2b fallback: strided gather from E (only if ws too small for ET)
__global__ void k_xe_direct(const float* __restrict__ xw, const int* __restrict__ xi,
                            const float* __restrict__ E, float* __restrict__ xe){
  int wid = blockIdx.x*(blockDim.x>>6) + (threadIdx.x>>6);
  int lane = threadIdx.x & 63;
  if (wid >= NN) return;
  const float* w = xw + wid*KW;
  const int*   v = xi + wid*KW;
  const float* Erow = E + (size_t)lane*VC;
  float acc = 0.f;
  for (int k = 0; k < KW; ++k) acc += w[k] * Erow[v[k]];
  xe[wid*64 + lane] = acc;
}

// -------- K3: fused node transform (leaf GRU + parent precompute) --------
__global__ void __launch_bounds__(256) k_node(const float* __restrict__ xe,
    const float* __restrict__ WzT, const float* __restrict__ WrT,
    const float* __restrict__ WhT, const float* __restrict__ Wa,
    const float* __restrict__ bz, const float* __restrict__ br,
    const float* __restrict__ bh,
    float* __restrict__ node_h, float* __restrict__ pz, float* __restrict__ pr,
    float* __restrict__ pc, float* __restrict__ qa){
  int wid = blockIdx.x*(blockDim.x>>6) + (threadIdx.x>>6);
  int lane = threadIdx.x & 63;
  if (wid >= NN) return;
  float xev = xe[wid*64 + lane];
  if (wid < NL){
    float az0=0.f, az1=0.f, ah0=0.f, ah1=0.f;
    #pragma unroll 8
    for (int k=0;k<64;k+=2){
      float x0 = __shfl(xev, k), x1 = __shfl(xev, k+1);
      az0 += x0 * WzT[k*64+lane];     az1 += x1 * WzT[(k+1)*64+lane];
      ah0 += x0 * WhT[k*64+lane];     ah1 += x1 * WhT[(k+1)*64+lane];
    }
    float z = sigmoidf_(az0+az1 + bz[lane]);
    float c = tanhf(ah0+ah1 + bh[lane]);
    node_h[wid*64+lane] = (1.f-z)*c;
  } else {
    int i = wid - NL;
    float az=0.f, ar=0.f, ah=0.f, aq=0.f;
    #pragma unroll 4
    for (int k=0;k<64;++k){
      float xk = __shfl(xev, k);
      az += xk * WzT[k*64+lane];
      ar += xk * WrT[k*64+lane];
      ah += xk * WhT[k*64+lane];
      aq += xk * Wa [k*64+lane];
    }
    pz[i*64+lane] = az + bz[lane];
    pr[i*64+lane] = ar + br[lane];
    pc[i*64+lane] = ah + bh[lane];
    qa[i*64+lane] = aq;
  }
}

// ---- shared GRU math: returns h[lane] given child vectors + prefetched pre-rows ----
__device__ __forceinline__ float gru_compute(int lane,
    int c0,int c1,int c2,int c3,
    float chv0,float chv1,float chv2,float chv3,
    float q, float pzv, float prv, float pcv,
    const float* __restrict__ UzT, const float* __restrict__ UrT,
    const float* __restrict__ UhT)
{
  float d0=q*chv0, d1=q*chv1, d2=q*chv2, d3=q*chv3;
  #pragma unroll
  for (int off=32; off; off>>=1){
    d0 += __shfl_xor(d0, off); d1 += __shfl_xor(d1, off);
    d2 += __shfl_xor(d2, off); d3 += __shfl_xor(d3, off);
  }
  float l0 = (c0>=0)? sigmoidf_(d0) : -1e30f;
  float l1 = (c1>=0)? sigmoidf_(d1) : -1e30f;
  float l2 = (c2>=0)? sigmoidf_(d2) : -1e30f;
  float l3 = (c3>=0)? sigmoidf_(d3) : -1e30f;
  float mx = fmaxf(fmaxf(l0,l1), fmaxf(l2,l3));
  float e0=expf(l0-mx), e1=expf(l1-mx), e2=expf(l2-mx), e3=expf(l3-mx);
  float inv = 1.f/(e0+e1+e2+e3);
  float ht = (e0*chv0 + e1*chv1 + e2*chv2 + e3*chv3)*inv;
  float az0=0.f, az1=0.f, ar0=0.f, ar1=0.f;
  #pragma unroll 8
  for (int k=0;k<64;k+=2){
    float h0 = __shfl(ht, k), h1 = __shfl(ht, k+1);
    az0 += h0 * UzT[k*64+lane];     az1 += h1 * UzT[(k+1)*64+lane];
    ar0 += h0 * UrT[k*64+lane];     ar1 += h1 * UrT[(k+1)*64+lane];
  }
  float z = sigmoidf_(pzv + az0+az1);
  float r = sigmoidf_(prv + ar0+ar1);
  float rh = r*ht;
  float ac0=0.f, ac1=0.f, ac2=0.f, ac3=0.f;
  #pragma unroll 8
  for (int k=0;k<64;k+=4){
    float r0 = __shfl(rh, k),   r1 = __shfl(rh, k+1);
    float r2 = __shfl(rh, k+2), r3 = __shfl(rh, k+3);
    ac0 += r0 * UhT[k*64+lane];     ac1 += r1 * UhT[(k+1)*64+lane];
    ac2 += r2 * UhT[(k+2)*64+lane]; ac3 += r3 * UhT[(k+3)*64+lane];
  }
  float cc = tanhf(pcv + (ac0+ac1)+(ac2+ac3));
  return z*ht + (1.f-z)*cc;
}

// ---- K4: single-dispatch dataflow scan ----
// One wave per parent (grid = NP/4 blocks). Sentinel-in-data: parent rows start
// as SENT. Consume: atomicCAS(p,SENT,SENT) — a GENUINE RMW (never folded to a
// load, unlike atomicOr(p,0)) that executes at the L3 coherence point; identity
// when the row is still SENT. Publish: per-lane atomicExch (proven to land at L3,
// r3/r6). No fences, no flags, no ordering protocol: each dword is independently
// valid when != SENT. Bounded spin; on timeout, write NOTHING (cleanup backstop
// finishes next dispatch). Progress needs no co-residency: children have strictly
// smaller indices, blocks dispatch in ascending order.
__global__ void __launch_bounds__(256) k_dflow(const int* __restrict__ tree,
    const float* __restrict__ qa, const float* __restrict__ pz,
    const float* __restrict__ pr, const float* __restrict__ pc,
    const float* __restrict__ UzT, const float* __restrict__ UrT,
    const float* __restrict__ UhT,
    float* node_h, int* done, int* g_rem)
{
  int w = threadIdx.x >> 6, lane = threadIdx.x & 63;
  int i = blockIdx.x*4 + w;
  if (i >= NP) return;
  const int* tr = tree + i*5;
  int c0=tr[0], c1=tr[1], c2=tr[2], c3=tr[3];
  // prefetch pre-activations while (possibly) waiting on children
  float q   = qa[i*64+lane];
  float pzv = pz[i*64+lane];
  float prv = pr[i*64+lane];
  float pcv = pc[i*64+lane];
  unsigned int* nhu = (unsigned int*)node_h;
  float chv[4];
  bool ok = true;
  #pragma unroll
  for (int j=0;j<4;++j){
    int c = (j==0)?c0:(j==1)?c1:(j==2)?c2:c3;
    float v = 0.f;
    if (c >= 0 && c < NL){
      v = node_h[c*64+lane];                       // leaf: prior dispatch, plain load ok
    } else if (c >= NL){
      unsigned int* p = &nhu[(size_t)c*64 + lane];
      unsigned int u = atomicCAS(p, SENT, SENT);   // coherent RMW read @ L3
      int cnt = 0;
      while (__any((int)(u == SENT))){
        __builtin_amdgcn_s_sleep(32);              // ~2048 cyc backoff
        u = atomicCAS(p, SENT, SENT);
        if (++cnt > (1<<15)) break;                // ~40ms failsafe
      }
      if (__any((int)(u == SENT))){ ok = false; }
      v = __uint_as_float(u);
    }
    chv[j] = v;
  }
  if (!ok) return;                                 // leave for cleanup backstop
  float h = gru_compute(lane, c0,c1,c2,c3, chv[0],chv[1],chv[2],chv[3],
                        q, pzv, prv, pcv, UzT, UrT, UhT);
  atomicExch(&nhu[(size_t)(NL+i)*64 + lane], __float_as_uint(h));  // publish @ L3
  if (lane==0){ done[i] = 1; atomicAdd(g_rem, -1); }
}

__device__ __forceinline__ bool lvl_ready(int c, int lvl, const int* done){
  if (c < NL) return true;
  int e = done[c - NL];
  return (e > 0 && e < lvl);
}

// ------------- K5: single-block cleanup (guaranteed termination, proven) -------------
__global__ void __launch_bounds__(256) k_cleanup(const int* __restrict__ tree,
    const float* __restrict__ qa, const float* __restrict__ pz,
    const float* __restrict__ pr, const float* __restrict__ pc,
    const float* __restrict__ UzT, const float* __restrict__ UrT,
    const float* __restrict__ UhT,
    float* node_h, int* done, int* g_rem)
{
  int rem = *g_rem;
  if (rem <= 0) return;
  __shared__ int cnt_s;
  int w = threadIdx.x >> 6, lane = threadIdx.x & 63;
  int epoch = CLEAN_EPOCH;
  while (rem > 0){
    if (threadIdx.x == 0) cnt_s = 0;
    __syncthreads();
    int my = 0;
    for (int i = w; i < NP; i += 4){
      if (done[i]) continue;
      const int* tr = tree + i*5;
      int c0=tr[0], c1=tr[1], c2=tr[2], c3=tr[3];
      if (!(lvl_ready(c0,epoch,done) && lvl_ready(c1,epoch,done)
         && lvl_ready(c2,epoch,done) && lvl_ready(c3,epoch,done))) continue;
      float chv0 = (c0>=0)? node_h[c0*64+lane] : 0.f;
      float chv1 = (c1>=0)? node_h[c1*64+lane] : 0.f;
      float chv2 = (c2>=0)? node_h[c2*64+lane] : 0.f;
      float chv3 = (c3>=0)? node_h[c3*64+lane] : 0.f;
      float h = gru_compute(lane, c0,c1,c2,c3, chv0,chv1,chv2,chv3,
                            qa[i*64+lane], pz[i*64+lane], pr[i*64+lane], pc[i*64+lane],
                            UzT, UrT, UhT);
      node_h[(size_t)(NL+i)*64+lane] = h;
      if (lane==0) done[i] = epoch;
      ++my;
    }
    if (lane==0 && my) atomicAdd(&cnt_s, my);
    __syncthreads();
    rem -= cnt_s;
    ++epoch;
    __syncthreads();
  }
}

// ---------------- K6a/K6b: max-pool + head ----------------
__global__ void k_max1(const float* __restrict__ node_h, float* __restrict__ partial){
  __shared__ float sm[4][64];
  int lane = threadIdx.x & 63, w = threadIdx.x>>6;
  int base = NL + blockIdx.x*128;
  float m = -1e30f;
  for (int r = w; r < 128; r += 4)
    m = fmaxf(m, node_h[(size_t)(base+r)*64 + lane]);
  sm[w][lane] = m;
  __syncthreads();
  if (w==0){
    m = fmaxf(fmaxf(sm[0][lane],sm[1][lane]), fmaxf(sm[2][lane],sm[3][lane]));
    partial[blockIdx.x*64+lane] = m;
  }
}

__global__ void k_max2(const float* __restrict__ partial, const float* __restrict__ Wout,
                       const float* __restrict__ bout, float* __restrict__ out){
  int lane = threadIdx.x;   // 64 threads = 1 wave
  float m = -1e30f;
  for (int b=0;b<64;++b) m = fmaxf(m, partial[b*64+lane]);
  float s0 = Wout[0*64+lane]*m;
  float s1 = Wout[1*64+lane]*m;
  float s2 = Wout[2*64+lane]*m;
  float s3 = Wout[3*64+lane]*m;
  #pragma unroll
  for (int off=32; off; off>>=1){
    s0 += __shfl_xor(s0, off);
    s1 += __shfl_xor(s1, off);
    s2 += __shfl_xor(s2, off);
    s3 += __shfl_xor(s3, off);
  }
  s0 += bout[0]; s1 += bout[1]; s2 += bout[2]; s3 += bout[3];
  float mx = fmaxf(fmaxf(s0,s1), fmaxf(s2,s3));
  float e0=expf(s0-mx), e1=expf(s1-mx), e2=expf(s2-mx), e3=expf(s3-mx);
  float inv = 1.f/(e0+e1+e2+e3);
  if (lane==0){
    out[0]=e0*inv; out[1]=e1*inv; out[2]=e2*inv; out[3]=e3*inv;
  }
}

__global__ void k_ws_sentinel(float* out, float wsmb){
  if (threadIdx.x < 4) out[threadIdx.x] = wsmb;
}

extern "C" void kernel_launch(void* const* d_in, const int* in_sizes, int n_in,
                              void* d_out, int out_size, void* d_ws, size_t ws_size,
                              hipStream_t stream){
  const float* x_word = (const float*)d_in[0];
  const int*   x_index= (const int*)d_in[1];
  const int*   tree   = (const int*)d_in[2];
  const float* E      = (const float*)d_in[3];
  const float* Wz     = (const float*)d_in[4];
  const float* Uz     = (const float*)d_in[5];
  const float* bz     = (const float*)d_in[6];
  const float* Wr     = (const float*)d_in[7];
  const float* Ur     = (const float*)d_in[8];
  const float* br     = (const float*)d_in[9];
  const float* Wh     = (const float*)d_in[10];
  const float* Uh     = (const float*)d_in[11];
  const float* bh     = (const float*)d_in[12];
  const float* Wa     = (const float*)d_in[13];
  const float* Wout   = (const float*)d_in[14];
  const float* bout   = (const float*)d_in[15];
  float* out = (float*)d_out;

  float* ws = (float*)d_ws;

  // r6-proven footprint (34.1 MB): region0 = ET (6,400,000 f) during {setup, xe};
  // after k_xe it is reused for qa/pz/pr/pc (2,097,152) + part (4,096).
  // Tail (never aliased): xe | nodeh | WT | done | g_rem.
  const size_t R0_FULL = 6400000;
  const size_t R0_FB   = 2101248;            // qa..pc + part
  const size_t TAIL    = 1048576 + 1048576 + 24576 + NP + 1;
  const size_t FULL_NEED = (R0_FULL + TAIL) * 4;   // ~34.1 MB (proven in r6/r7)
  const size_t FB_NEED   = (R0_FB   + TAIL) * 4;   // ~16.9 MB

  bool full = (ws_size >= FULL_NEED);
  bool fb   = (!full && ws_size >= FB_NEED);
  if (!full && !fb){
    k_ws_sentinel<<<1, 64, 0, stream>>>(out, (float)(ws_size >> 20));
    return;
  }

  float* qa    = ws;                        // 4 x 524,288 (aliases ET; ET dead after k_xe)
  float* pz    = qa + 524288;
  float* pr    = pz + 524288;
  float* pc    = pr + 524288;
  float* part  = pc + 524288;               // 4,096 f
  float* ET    = ws;                        // full path only
  size_t r0    = full ? R0_FULL : R0_FB;
  float* xe    = ws + r0;                   // 1,048,576 f
  float* nodeh = xe + 1048576;              // 1,048,576 f
  float* WT    = nodeh + 1048576;           // 24,576 f
  int*   done  = (int*)(WT + 24576);        // NP
  int*   g_rem = done + NP;                 // 1
  float* WzT = WT,       *WrT = WT+4096,  *WhT = WT+8192;
  float* UzT = WT+12288, *UrT = WT+16384, *UhT = WT+20480;

  // Parent rows of node_h -> SENT (kernel-boundary release makes this visible).
  hipMemsetAsync(nodeh + (size_t)NL*64, 0xFF, (size_t)NP*64*4, stream);

  int et_blocks = full ? (VC+63)/64 : 0;    // 1563 or 0
  k_setup<<<et_blocks + 6 + NP/256, 256, 0, stream>>>(E, ET, Wz, Wr, Wh, Uz, Ur, Uh,
                                                      WT, done, g_rem, et_blocks);
  if (full) k_xe       <<<NN/4, 256, 0, stream>>>(x_word, x_index, ET, xe);
  else      k_xe_direct<<<NN/4, 256, 0, stream>>>(x_word, x_index, E, xe);
  k_node <<<NN/4, 256, 0, stream>>>(xe, WzT, WrT, WhT, Wa, bz, br, bh,
                                    nodeh, pz, pr, pc, qa);
  k_dflow<<<NP/4, 256, 0, stream>>>(tree, qa, pz, pr, pc, UzT, UrT, UhT,
                                    nodeh, done, g_rem);
  k_cleanup<<<1,  256, 0, stream>>>(tree, qa, pz, pr, pc, UzT, UrT, UhT,
                                    nodeh, done, g_rem);
  k_max1   <<<64, 256, 0, stream>>>(nodeh, part);
  k_max2   <<<1,   64, 0, stream>>>(part, Wout, bout, out);
}

// Round 11
// 184.041 us; speedup vs baseline: 1.5090x; 1.1002x over previous
//
#include <hip/hip_runtime.h>
#include <math.h>

#define NN 16384
#define NP 8192
#define NL 8192
#define KW 32
#define VC 100000
#define SENT  0xFFFFFFFFu
#define NEVER 0xFFFFFFFEu   // impossible bit pattern for GRU output; CAS compare always fails => pure coherent read
#define CLEAN_EPOCH 1000

__device__ __forceinline__ float sigmoidf_(float x){ return 1.0f/(1.0f+expf(-x)); }

// ---- K1: fused setup: E-transpose + weight transposes + SENT init + done/g_rem ----
__global__ void __launch_bounds__(256) k_setup(const float* __restrict__ E, float* __restrict__ ET,
    const float* __restrict__ Wz, const float* __restrict__ Wr, const float* __restrict__ Wh,
    const float* __restrict__ Uz, const float* __restrict__ Ur, const float* __restrict__ Uh,
    float* __restrict__ WT, float* __restrict__ node_h, int* done, int* g_rem, int et_blocks){
  __shared__ float tile[64][65];
  int b = blockIdx.x;
  int lane = threadIdx.x & 63, ty = threadIdx.x >> 6;
  if (b < et_blocks){
    int v0 = b*64;
    for (int h = ty; h < 64; h += 4){
      int v = v0 + lane;
      tile[h][lane] = (v < VC) ? E[(size_t)h*VC + v] : 0.f;
    }
    __syncthreads();
    for (int vv = ty; vv < 64; vv += 4){
      int v = v0 + vv;
      if (v < VC) ET[v*64 + lane] = tile[lane][vv];
    }
  } else if (b < et_blocks + 6){
    int m = b - et_blocks;
    const float* src = (m==0)?Wz:(m==1)?Wr:(m==2)?Wh:(m==3)?Uz:(m==4)?Ur:Uh;
    float* dst = WT + m*4096;
    for (int h = ty; h < 64; h += 4) tile[h][lane] = src[h*64 + lane];
    __syncthreads();
    for (int k = ty; k < 64; k += 4) dst[k*64 + lane] = tile[lane][k];
  } else if (b < et_blocks + 6 + 2048){
    // parent rows of node_h -> SENT  (NP*64 = 524,288 dwords over 2048 blocks)
    size_t idx = (size_t)(b - et_blocks - 6)*256 + threadIdx.x;
    ((unsigned int*)node_h)[(size_t)NL*64 + idx] = SENT;
  } else {
    int idx = (b - et_blocks - 6 - 2048)*256 + threadIdx.x;
    if (idx < NP) done[idx] = 0;
    if (idx == 0) *g_rem = NP;
  }
}

// -------- shared node-transform body (leaf GRU + parent precompute) --------
__device__ __forceinline__ void node_body(int wid, int lane, float xev,
    const float* __restrict__ WzT, const float* __restrict__ WrT,
    const float* __restrict__ WhT, const float* __restrict__ Wa,
    const float* __restrict__ bz, const float* __restrict__ br,
    const float* __restrict__ bh,
    float* __restrict__ node_h, float* __restrict__ pz, float* __restrict__ pr,
    float* __restrict__ pc, float* __restrict__ qa){
  if (wid < NL){
    float az0=0.f, az1=0.f, ah0=0.f, ah1=0.f;
    #pragma unroll 8
    for (int k=0;k<64;k+=2){
      float x0 = __shfl(xev, k), x1 = __shfl(xev, k+1);
      az0 += x0 * WzT[k*64+lane];     az1 += x1 * WzT[(k+1)*64+lane];
      ah0 += x0 * WhT[k*64+lane];     ah1 += x1 * WhT[(k+1)*64+lane];
    }
    float z = sigmoidf_(az0+az1 + bz[lane]);
    float c = tanhf(ah0+ah1 + bh[lane]);
    node_h[wid*64+lane] = (1.f-z)*c;
  } else {
    int i = wid - NL;
    float az=0.f, ar=0.f, ah=0.f, aq=0.f;
    #pragma unroll 4
    for (int k=0;k<64;++k){
      float xk = __shfl(xev, k);
      az += xk * WzT[k*64+lane];
      ar += xk * WrT[k*64+lane];
      ah += xk * WhT[k*64+lane];
      aq += xk * Wa [k*64+lane];
    }
    pz[i*64+lane] = az + bz[lane];
    pr[i*64+lane] = ar + br[lane];
    pc[i*64+lane] = ah + bh[lane];
    qa[i*64+lane] = aq;
  }
}

// ---- K2: FUSED xe-gather + node transform (one wave per node) ----
__global__ void __launch_bounds__(256) k_xenode(const float* __restrict__ xw,
    const int* __restrict__ xi, const float* __restrict__ ET,
    const float* __restrict__ WzT, const float* __restrict__ WrT,
    const float* __restrict__ WhT, const float* __restrict__ Wa,
    const float* __restrict__ bz, const float* __restrict__ br,
    const float* __restrict__ bh,
    float* __restrict__ node_h, float* __restrict__ pz, float* __restrict__ pr,
    float* __restrict__ pc, float* __restrict__ qa){
  int wid = blockIdx.x*(blockDim.x>>6) + (threadIdx.x>>6);
  int lane = threadIdx.x & 63;
  if (wid >= NN) return;
  int   idxl = (lane < KW) ? xi[wid*KW + lane] : 0;
  float wl   = (lane < KW) ? xw[wid*KW + lane] : 0.f;
  float xev = 0.f;
  #pragma unroll 8
  for (int k = 0; k < KW; ++k){
    int   vk = __shfl(idxl, k);
    float wk = __shfl(wl,   k);
    xev += wk * ET[vk*64 + lane];
  }
  node_body(wid, lane, xev, WzT,WrT,WhT,Wa, bz,br,bh, node_h, pz,pr,pc, qa);
}

// K2b fallback: strided gather from E (only if ws too small for ET)
__global__ void __launch_bounds__(256) k_xenode_direct(const float* __restrict__ xw,
    const int* __restrict__ xi, const float* __restrict__ E,
    const float* __restrict__ WzT, const float* __restrict__ WrT,
    const float* __restrict__ WhT, const float* __restrict__ Wa,
    const float* __restrict__ bz, const float* __restrict__ br,
    const float* __restrict__ bh,
    float* __restrict__ node_h, float* __restrict__ pz, float* __restrict__ pr,
    float* __restrict__ pc, float* __restrict__ qa){
  int wid = blockIdx.x*(blockDim.x>>6) + (threadIdx.x>>6);
  int lane = threadIdx.x & 63;
  if (wid >= NN) return;
  const float* w = xw + wid*KW;
  const int*   v = xi + wid*KW;
  const float* Erow = E + (size_t)lane*VC;
  float xev = 0.f;
  for (int k = 0; k < KW; ++k) xev += w[k] * Erow[v[k]];
  node_body(wid, lane, xev, WzT,WrT,WhT,Wa, bz,br,bh, node_h, pz,pr,pc, qa);
}

// ---- shared GRU math: returns h[lane] given child vectors + prefetched pre-rows ----
__device__ __forceinline__ float gru_compute(int lane,
    int c0,int c1,int c2,int c3,
    float chv0,float chv1,float chv2,float chv3,
    float q, float pzv, float prv, float pcv,
    const float* __restrict__ UzT, const float* __restrict__ UrT,
    const float* __restrict__ UhT)
{
  float d0=q*chv0, d1=q*chv1, d2=q*chv2, d3=q*chv3;
  #pragma unroll
  for (int off=32; off; off>>=1){
    d0 += __shfl_xor(d0, off); d1 += __shfl_xor(d1, off);
    d2 += __shfl_xor(d2, off); d3 += __shfl_xor(d3, off);
  }
  float l0 = (c0>=0)? sigmoidf_(d0) : -1e30f;
  float l1 = (c1>=0)? sigmoidf_(d1) : -1e30f;
  float l2 = (c2>=0)? sigmoidf_(d2) : -1e30f;
  float l3 = (c3>=0)? sigmoidf_(d3) : -1e30f;
  float mx = fmaxf(fmaxf(l0,l1), fmaxf(l2,l3));
  float e0=expf(l0-mx), e1=expf(l1-mx), e2=expf(l2-mx), e3=expf(l3-mx);
  float inv = 1.f/(e0+e1+e2+e3);
  float ht = (e0*chv0 + e1*chv1 + e2*chv2 + e3*chv3)*inv;
  float az0=0.f, az1=0.f, ar0=0.f, ar1=0.f;
  #pragma unroll 8
  for (int k=0;k<64;k+=2){
    float h0 = __shfl(ht, k), h1 = __shfl(ht, k+1);
    az0 += h0 * UzT[k*64+lane];     az1 += h1 * UzT[(k+1)*64+lane];
    ar0 += h0 * UrT[k*64+lane];     ar1 += h1 * UrT[(k+1)*64+lane];
  }
  float z = sigmoidf_(pzv + az0+az1);
  float r = sigmoidf_(prv + ar0+ar1);
  float rh = r*ht;
  float ac0=0.f, ac1=0.f, ac2=0.f, ac3=0.f;
  #pragma unroll 8
  for (int k=0;k<64;k+=4){
    float r0 = __shfl(rh, k),   r1 = __shfl(rh, k+1);
    float r2 = __shfl(rh, k+2), r3 = __shfl(rh, k+3);
    ac0 += r0 * UhT[k*64+lane];     ac1 += r1 * UhT[(k+1)*64+lane];
    ac2 += r2 * UhT[(k+2)*64+lane]; ac3 += r3 * UhT[(k+3)*64+lane];
  }
  float cc = tanhf(pcv + (ac0+ac1)+(ac2+ac3));
  return z*ht + (1.f-z)*cc;
}

// ---- K3: single-dispatch dataflow scan (r10-proven; polls now write-free) ----
// Sentinel-in-data: parent rows start SENT; rows transition SENT->final exactly once
// (monotone), so a stale cached read can only err toward SENT -> routed to CAS path.
// Poll = atomicCAS(p, NEVER, NEVER): compare always fails -> genuine RMW read at the
// L3 coherence point, ZERO write traffic (r10's SENT-compare CAS succeeded while
// waiting and wrote 28MB of dirty lines). Fast path: plain wave-load (no atomics).
// While waiting: lane0 polls element 0 only (1/64th the RMW traffic), then lagging
// lanes CAS-read once. Publish via per-lane atomicExch (proven at L3).
__global__ void __launch_bounds__(256) k_dflow(const int* __restrict__ tree,
    const float* __restrict__ qa, const float* __restrict__ pz,
    const float* __restrict__ pr, const float* __restrict__ pc,
    const float* __restrict__ UzT, const float* __restrict__ UrT,
    const float* __restrict__ UhT,
    float* node_h, int* done, int* g_rem)
{
  int w = threadIdx.x >> 6, lane = threadIdx.x & 63;
  int i = blockIdx.x*4 + w;
  if (i >= NP) return;
  const int* tr = tree + i*5;
  int c0=tr[0], c1=tr[1], c2=tr[2], c3=tr[3];
  float q   = qa[i*64+lane];
  float pzv = pz[i*64+lane];
  float prv = pr[i*64+lane];
  float pcv = pc[i*64+lane];
  unsigned int* nhu = (unsigned int*)node_h;
  float chv[4];
  bool ok = true;
  #pragma unroll
  for (int j=0;j<4;++j){
    int c = (j==0)?c0:(j==1)?c1:(j==2)?c2:c3;
    float v = 0.f;
    if (c >= 0 && c < NL){
      v = node_h[c*64+lane];                       // leaf: prior dispatch, plain load
    } else if (c >= NL){
      unsigned int u = nhu[(size_t)c*64 + lane];   // fast path: plain wave-load
      int rounds = 0;
      while (__any((int)(u == SENT)) && rounds < (1<<16)){
        if (lane == 0){
          unsigned int s0 = atomicCAS(&nhu[(size_t)c*64], NEVER, NEVER);
          while (s0 == SENT && rounds < (1<<16)){
            __builtin_amdgcn_s_sleep(16);          // ~1024 cyc
            ++rounds;
            s0 = atomicCAS(&nhu[(size_t)c*64], NEVER, NEVER);
          }
        }
        rounds = __shfl(rounds, 0) + 1;
        if (u == SENT) u = atomicCAS(&nhu[(size_t)c*64 + lane], NEVER, NEVER);
        if (__any((int)(u == SENT))) __builtin_amdgcn_s_sleep(4);
      }
      if (__any((int)(u == SENT))) ok = false;     // failsafe: leave for cleanup
      v = __uint_as_float(u);
    }
    chv[j] = v;
  }
  if (!ok) return;
  float h = gru_compute(lane, c0,c1,c2,c3, chv[0],chv[1],chv[2],chv[3],
                        q, pzv, prv, pcv, UzT, UrT, UhT);
  atomicExch(&nhu[(size_t)(NL+i)*64 + lane], __float_as_uint(h));   // publish @ L3
  if (lane==0){ done[i] = 1; atomicAdd(g_rem, -1); }
}

__device__ __forceinline__ bool lvl_ready(int c, int lvl, const int* done){
  if (c < NL) return true;
  int e = done[c - NL];
  return (e > 0 && e < lvl);
}

// ------------- K4: single-block cleanup (guaranteed termination backstop) -------------
__global__ void __launch_bounds__(256) k_cleanup(const int* __restrict__ tree,
    const float* __restrict__ qa, const float* __restrict__ pz,
    const float* __restrict__ pr, const float* __restrict__ pc,
    const float* __restrict__ UzT, const float* __restrict__ UrT,
    const float* __restrict__ UhT,
    float* node_h, int* done, int* g_rem)
{
  int rem = *g_rem;
  if (rem <= 0) return;
  __shared__ int cnt_s;
  int w = threadIdx.x >> 6, lane = threadIdx.x & 63;
  int epoch = CLEAN_EPOCH;
  while (rem > 0){
    if (threadIdx.x == 0) cnt_s = 0;
    __syncthreads();
    int my = 0;
    for (int i = w; i < NP; i += 4){
      if (done[i]) continue;
      const int* tr = tree + i*5;
      int c0=tr[0], c1=tr[1], c2=tr[2], c3=tr[3];
      if (!(lvl_ready(c0,epoch,done) && lvl_ready(c1,epoch,done)
         && lvl_ready(c2,epoch,done) && lvl_ready(c3,epoch,done))) continue;
      float chv0 = (c0>=0)? node_h[c0*64+lane] : 0.f;
      float chv1 = (c1>=0)? node_h[c1*64+lane] : 0.f;
      float chv2 = (c2>=0)? node_h[c2*64+lane] : 0.f;
      float chv3 = (c3>=0)? node_h[c3*64+lane] : 0.f;
      float h = gru_compute(lane, c0,c1,c2,c3, chv0,chv1,chv2,chv3,
                            qa[i*64+lane], pz[i*64+lane], pr[i*64+lane], pc[i*64+lane],
                            UzT, UrT, UhT);
      node_h[(size_t)(NL+i)*64+lane] = h;
      if (lane==0) done[i] = epoch;
      ++my;
    }
    if (lane==0 && my) atomicAdd(&cnt_s, my);
    __syncthreads();
    rem -= cnt_s;
    ++epoch;
    __syncthreads();
  }
}

// ---------------- K5a/K5b: max-pool + head ----------------
__global__ void k_max1(const float* __restrict__ node_h, float* __restrict__ partial){
  __shared__ float sm[4][64];
  int lane = threadIdx.x & 63, w = threadIdx.x>>6;
  int base = NL + blockIdx.x*128;
  float m = -1e30f;
  for (int r = w; r < 128; r += 4)
    m = fmaxf(m, node_h[(size_t)(base+r)*64 + lane]);
  sm[w][lane] = m;
  __syncthreads();
  if (w==0){
    m = fmaxf(fmaxf(sm[0][lane],sm[1][lane]), fmaxf(sm[2][lane],sm[3][lane]));
    partial[blockIdx.x*64+lane] = m;
  }
}

__global__ void k_max2(const float* __restrict__ partial, const float* __restrict__ Wout,
                       const float* __restrict__ bout, float* __restrict__ out){
  int lane = threadIdx.x;   // 64 threads = 1 wave
  float m = -1e30f;
  for (int b=0;b<64;++b) m = fmaxf(m, partial[b*64+lane]);
  float s0 = Wout[0*64+lane]*m;
  float s1 = Wout[1*64+lane]*m;
  float s2 = Wout[2*64+lane]*m;
  float s3 = Wout[3*64+lane]*m;
  #pragma unroll
  for (int off=32; off; off>>=1){
    s0 += __shfl_xor(s0, off);
    s1 += __shfl_xor(s1, off);
    s2 += __shfl_xor(s2, off);
    s3 += __shfl_xor(s3, off);
  }
  s0 += bout[0]; s1 += bout[1]; s2 += bout[2]; s3 += bout[3];
  float mx = fmaxf(fmaxf(s0,s1), fmaxf(s2,s3));
  float e0=expf(s0-mx), e1=expf(s1-mx), e2=expf(s2-mx), e3=expf(s3-mx);
  float inv = 1.f/(e0+e1+e2+e3);
  if (lane==0){
    out[0]=e0*inv; out[1]=e1*inv; out[2]=e2*inv; out[3]=e3*inv;
  }
}

__global__ void k_ws_sentinel(float* out, float wsmb){
  if (threadIdx.x < 4) out[threadIdx.x] = wsmb;
}

extern "C" void kernel_launch(void* const* d_in, const int* in_sizes, int n_in,
                              void* d_out, int out_size, void* d_ws, size_t ws_size,
                              hipStream_t stream){
  const float* x_word = (const float*)d_in[0];
  const int*   x_index= (const int*)d_in[1];
  const int*   tree   = (const int*)d_in[2];
  const float* E      = (const float*)d_in[3];
  const float* Wz     = (const float*)d_in[4];
  const float* Uz     = (const float*)d_in[5];
  const float* bz     = (const float*)d_in[6];
  const float* Wr     = (const float*)d_in[7];
  const float* Ur     = (const float*)d_in[8];
  const float* br     = (const float*)d_in[9];
  const float* Wh     = (const float*)d_in[10];
  const float* Uh     = (const float*)d_in[11];
  const float* bh     = (const float*)d_in[12];
  const float* Wa     = (const float*)d_in[13];
  const float* Wout   = (const float*)d_in[14];
  const float* bout   = (const float*)d_in[15];
  float* out = (float*)d_out;

  float* ws = (float*)d_ws;

  // Layout: ET (6,400,000 f) read by k_xenode, so everything k_xenode WRITES lives in
  // the tail. Only part (4,096 f, written by k_max1) aliases ET.
  // Tail: qa/pz/pr/pc (2,097,152) | nodeh (1,048,576) | WT (24,576) | done (NP) | g_rem.
  const size_t R0_FULL = 6400000;
  const size_t R0_FB   = 4096;               // part only
  const size_t TAIL    = 2097152 + 1048576 + 24576 + NP + 1;
  const size_t FULL_NEED = (R0_FULL + TAIL) * 4;   // ~38.3 MB (r8 ran full at ~38.7 MB)
  const size_t FB_NEED   = (R0_FB   + TAIL) * 4;   // ~12.7 MB

  bool full = (ws_size >= FULL_NEED);
  bool fb   = (!full && ws_size >= FB_NEED);
  if (!full && !fb){
    k_ws_sentinel<<<1, 64, 0, stream>>>(out, (float)(ws_size >> 20));
    return;
  }

  float* ET   = ws;                          // full path only; dead after k_xenode
  float* part = ws;                          // aliases ET; written only by k_max1
  size_t r0   = full ? R0_FULL : R0_FB;
  float* qa    = ws + r0;                    // 4 x 524,288
  float* pz    = qa + 524288;
  float* pr    = pz + 524288;
  float* pc    = pr + 524288;
  float* nodeh = pc + 524288;                // 1,048,576 f
  float* WT    = nodeh + 1048576;            // 24,576 f
  int*   done  = (int*)(WT + 24576);         // NP
  int*   g_rem = done + NP;                  // 1
  float* WzT = WT,       *WrT = WT+4096,  *WhT = WT+8192;
  float* UzT = WT+12288, *UrT = WT+16384, *UhT = WT+20480;

  int et_blocks = full ? (VC+63)/64 : 0;     // 1563 or 0
  k_setup<<<et_blocks + 6 + 2048 + NP/256, 256, 0, stream>>>(
      E, ET, Wz, Wr, Wh, Uz, Ur, Uh, WT, nodeh, done, g_rem, et_blocks);
  if (full)
    k_xenode<<<NN/4, 256, 0, stream>>>(x_word, x_index, ET, WzT, WrT, WhT, Wa,
                                       bz, br, bh, nodeh, pz, pr, pc, qa);
  else
    k_xenode_direct<<<NN/4, 256, 0, stream>>>(x_word, x_index, E, WzT, WrT, WhT, Wa,
                                              bz, br, bh, nodeh, pz, pr, pc, qa);
  k_dflow  <<<NP/4, 256, 0, stream>>>(tree, qa, pz, pr, pc, UzT, UrT, UhT,
                                      nodeh, done, g_rem);
  k_cleanup<<<1,    256, 0, stream>>>(tree, qa, pz, pr, pc, UzT, UrT, UhT,
                                      nodeh, done, g_rem);
  k_max1   <<<64,   256, 0, stream>>>(nodeh, part);
  k_max2   <<<1,     64, 0, stream>>>(part, Wout, bout, out);
}

// Round 12
// 164.142 us; speedup vs baseline: 1.6919x; 1.1212x over previous
//
#include <hip/hip_runtime.h>
#include <math.h>

#define NN 16384
#define NP 8192
#define NL 8192
#define KW 32
#define VC 100000
#define SENT  0xFFFFFFFFu
#define NEVER 0xFFFFFFFEu   // CAS compare-val that never matches GRU output -> pure coherent read, no write
#define CLEAN_EPOCH 1000

__device__ __forceinline__ float sigmoidf_(float x){ return 1.0f/(1.0f+expf(-x)); }

// ---- K1: setup: E-transpose + weight transposes + SENT init (ALL rows) + done/g_rem ----
__global__ void __launch_bounds__(256) k_setup(const float* __restrict__ E, float* __restrict__ ET,
    const float* __restrict__ Wz, const float* __restrict__ Wr, const float* __restrict__ Wh,
    const float* __restrict__ Uz, const float* __restrict__ Ur, const float* __restrict__ Uh,
    float* __restrict__ WT, float* __restrict__ node_h, int* done, int* g_rem, int et_blocks){
  __shared__ float tile[64][65];
  int b = blockIdx.x;
  int lane = threadIdx.x & 63, ty = threadIdx.x >> 6;
  if (b < et_blocks){
    int v0 = b*64;
    for (int h = ty; h < 64; h += 4){
      int v = v0 + lane;
      tile[h][lane] = (v < VC) ? E[(size_t)h*VC + v] : 0.f;
    }
    __syncthreads();
    for (int vv = ty; vv < 64; vv += 4){
      int v = v0 + vv;
      if (v < VC) ET[v*64 + lane] = tile[lane][vv];
    }
  } else if (b < et_blocks + 6){
    int m = b - et_blocks;
    const float* src = (m==0)?Wz:(m==1)?Wr:(m==2)?Wh:(m==3)?Uz:(m==4)?Ur:Uh;
    float* dst = WT + m*4096;
    for (int h = ty; h < 64; h += 4) tile[h][lane] = src[h*64 + lane];
    __syncthreads();
    for (int k = ty; k < 64; k += 4) dst[k*64 + lane] = tile[lane][k];
  } else if (b < et_blocks + 6 + 4096){
    // ALL node rows -> SENT (leaves are now published inside the same dispatch that
    // consumes them, so they need the sentinel protocol too). NN*64 = 1,048,576 dwords.
    size_t idx = (size_t)(b - et_blocks - 6)*256 + threadIdx.x;
    ((unsigned int*)node_h)[idx] = SENT;
  } else {
    int idx = (b - et_blocks - 6 - 4096)*256 + threadIdx.x;
    if (idx < NP) done[idx] = 0;
    if (idx == 0) *g_rem = NP;
  }
}

// ---- shared GRU math: returns h[lane] given child vectors + pre-activations ----
__device__ __forceinline__ float gru_compute(int lane,
    int c0,int c1,int c2,int c3,
    float chv0,float chv1,float chv2,float chv3,
    float q, float pzv, float prv, float pcv,
    const float* __restrict__ UzT, const float* __restrict__ UrT,
    const float* __restrict__ UhT)
{
  float d0=q*chv0, d1=q*chv1, d2=q*chv2, d3=q*chv3;
  #pragma unroll
  for (int off=32; off; off>>=1){
    d0 += __shfl_xor(d0, off); d1 += __shfl_xor(d1, off);
    d2 += __shfl_xor(d2, off); d3 += __shfl_xor(d3, off);
  }
  float l0 = (c0>=0)? sigmoidf_(d0) : -1e30f;
  float l1 = (c1>=0)? sigmoidf_(d1) : -1e30f;
  float l2 = (c2>=0)? sigmoidf_(d2) : -1e30f;
  float l3 = (c3>=0)? sigmoidf_(d3) : -1e30f;
  float mx = fmaxf(fmaxf(l0,l1), fmaxf(l2,l3));
  float e0=expf(l0-mx), e1=expf(l1-mx), e2=expf(l2-mx), e3=expf(l3-mx);
  float inv = 1.f/(e0+e1+e2+e3);
  float ht = (e0*chv0 + e1*chv1 + e2*chv2 + e3*chv3)*inv;
  float az0=0.f, az1=0.f, ar0=0.f, ar1=0.f;
  #pragma unroll 8
  for (int k=0;k<64;k+=2){
    float h0 = __shfl(ht, k), h1 = __shfl(ht, k+1);
    az0 += h0 * UzT[k*64+lane];     az1 += h1 * UzT[(k+1)*64+lane];
    ar0 += h0 * UrT[k*64+lane];     ar1 += h1 * UrT[(k+1)*64+lane];
  }
  float z = sigmoidf_(pzv + az0+az1);
  float r = sigmoidf_(prv + ar0+ar1);
  float rh = r*ht;
  float ac0=0.f, ac1=0.f, ac2=0.f, ac3=0.f;
  #pragma unroll 8
  for (int k=0;k<64;k+=4){
    float r0 = __shfl(rh, k),   r1 = __shfl(rh, k+1);
    float r2 = __shfl(rh, k+2), r3 = __shfl(rh, k+3);
    ac0 += r0 * UhT[k*64+lane];     ac1 += r1 * UhT[(k+1)*64+lane];
    ac2 += r2 * UhT[(k+2)*64+lane]; ac3 += r3 * UhT[(k+3)*64+lane];
  }
  float cc = tanhf(pcv + (ac0+ac1)+(ac2+ac3));
  return z*ht + (1.f-z)*cc;
}

// ---- K2: FUSED xe-gather + node transform + single-dispatch dataflow scan ----
// One wave per node (leaves = blocks 0..2047 dispatch first; in-order block dispatch
// + children strictly lower-indexed => guaranteed progress; bounded spin + cleanup
// backstop catch pathology). Sentinel protocol r10/r11-proven:
//   publish  = per-lane atomicExch (lands at L3 coherence point)
//   fast read= plain wave-load (monotone SENT->final: stale can only read SENT, or the
//              previous replay's bit-identical value -> harmless)
//   poll     = atomicCAS(p,NEVER,NEVER): compare always fails -> coherent RMW read,
//              zero write traffic. All pending children polled CONCURRENTLY per pass.
__device__ __forceinline__ void fused_body(int wid, int lane, float xev,
    const float* __restrict__ WzT, const float* __restrict__ WrT,
    const float* __restrict__ WhT, const float* __restrict__ Wa,
    const float* __restrict__ bz, const float* __restrict__ br,
    const float* __restrict__ bh,
    const float* __restrict__ UzT, const float* __restrict__ UrT,
    const float* __restrict__ UhT, const int* __restrict__ tree,
    float* node_h, float* pz, float* pr, float* pc, float* qa,
    int* done, int* g_rem)
{
  unsigned int* nhu = (unsigned int*)node_h;
  if (wid < NL){
    float az0=0.f, az1=0.f, ah0=0.f, ah1=0.f;
    #pragma unroll 8
    for (int k=0;k<64;k+=2){
      float x0 = __shfl(xev, k), x1 = __shfl(xev, k+1);
      az0 += x0 * WzT[k*64+lane];     az1 += x1 * WzT[(k+1)*64+lane];
      ah0 += x0 * WhT[k*64+lane];     ah1 += x1 * WhT[(k+1)*64+lane];
    }
    float z = sigmoidf_(az0+az1 + bz[lane]);
    float c = tanhf(ah0+ah1 + bh[lane]);
    float h = (1.f-z)*c;
    atomicExch(&nhu[(size_t)wid*64 + lane], __float_as_uint(h));   // publish leaf @ L3
    return;
  }
  int i = wid - NL;
  float az=0.f, ar=0.f, ah=0.f, aq=0.f;
  #pragma unroll 4
  for (int k=0;k<64;++k){
    float xk = __shfl(xev, k);
    az += xk * WzT[k*64+lane];
    ar += xk * WrT[k*64+lane];
    ah += xk * WhT[k*64+lane];
    aq += xk * Wa [k*64+lane];
  }
  float pzv = az + bz[lane], prv = ar + br[lane], pcv = ah + bh[lane], q = aq;
  // store for the cleanup backstop (consumed from regs on the fast path)
  pz[i*64+lane] = pzv; pr[i*64+lane] = prv; pc[i*64+lane] = pcv; qa[i*64+lane] = q;
  const int* tr = tree + i*5;
  int c0=tr[0], c1=tr[1], c2=tr[2], c3=tr[3];
  // fast-path plain loads
  unsigned int u0 = (c0>=0)? nhu[(size_t)c0*64+lane] : 0u;
  unsigned int u1 = (c1>=0)? nhu[(size_t)c1*64+lane] : 0u;
  unsigned int u2 = (c2>=0)? nhu[(size_t)c2*64+lane] : 0u;
  unsigned int u3 = (c3>=0)? nhu[(size_t)c3*64+lane] : 0u;
  bool p0 = __any((int)(u0==SENT)), p1 = __any((int)(u1==SENT));
  bool p2 = __any((int)(u2==SENT)), p3 = __any((int)(u3==SENT));
  int rounds = 0;
  while ((p0|p1|p2|p3) && rounds < (1<<16)){
    if (p0){ if (u0==SENT) u0 = atomicCAS(&nhu[(size_t)c0*64+lane], NEVER, NEVER); p0 = __any((int)(u0==SENT)); }
    if (p1){ if (u1==SENT) u1 = atomicCAS(&nhu[(size_t)c1*64+lane], NEVER, NEVER); p1 = __any((int)(u1==SENT)); }
    if (p2){ if (u2==SENT) u2 = atomicCAS(&nhu[(size_t)c2*64+lane], NEVER, NEVER); p2 = __any((int)(u2==SENT)); }
    if (p3){ if (u3==SENT) u3 = atomicCAS(&nhu[(size_t)c3*64+lane], NEVER, NEVER); p3 = __any((int)(u3==SENT)); }
    if (p0|p1|p2|p3){ __builtin_amdgcn_s_sleep(4); ++rounds; }
  }
  if (p0|p1|p2|p3) return;                       // failsafe -> cleanup backstop
  float h = gru_compute(lane, c0,c1,c2,c3,
                        __uint_as_float(u0), __uint_as_float(u1),
                        __uint_as_float(u2), __uint_as_float(u3),
                        q, pzv, prv, pcv, UzT, UrT, UhT);
  atomicExch(&nhu[(size_t)(NL+i)*64 + lane], __float_as_uint(h));  // publish @ L3
  if (lane==0){ done[i] = 1; atomicAdd(g_rem, -1); }
}

__global__ void __launch_bounds__(256) k_fused(const float* __restrict__ xw,
    const int* __restrict__ xi, const float* __restrict__ ET,
    const float* __restrict__ WzT, const float* __restrict__ WrT,
    const float* __restrict__ WhT, const float* __restrict__ Wa,
    const float* __restrict__ bz, const float* __restrict__ br,
    const float* __restrict__ bh,
    const float* __restrict__ UzT, const float* __restrict__ UrT,
    const float* __restrict__ UhT, const int* __restrict__ tree,
    float* node_h, float* pz, float* pr, float* pc, float* qa,
    int* done, int* g_rem)
{
  int wid = blockIdx.x*4 + (threadIdx.x>>6);
  int lane = threadIdx.x & 63;
  if (wid >= NN) return;
  int   idxl = (lane < KW) ? xi[wid*KW + lane] : 0;
  float wl   = (lane < KW) ? xw[wid*KW + lane] : 0.f;
  float xev = 0.f;
  #pragma unroll 8
  for (int k = 0; k < KW; ++k){
    int   vk = __shfl(idxl, k);
    float wk = __shfl(wl,   k);
    xev += wk * ET[vk*64 + lane];
  }
  fused_body(wid, lane, xev, WzT,WrT,WhT,Wa, bz,br,bh, UzT,UrT,UhT, tree,
             node_h, pz,pr,pc,qa, done, g_rem);
}

// fallback variant: strided gather straight from E (only if ws too small for ET)
__global__ void __launch_bounds__(256) k_fused_direct(const float* __restrict__ xw,
    const int* __restrict__ xi, const float* __restrict__ E,
    const float* __restrict__ WzT, const float* __restrict__ WrT,
    const float* __restrict__ WhT, const float* __restrict__ Wa,
    const float* __restrict__ bz, const float* __restrict__ br,
    const float* __restrict__ bh,
    const float* __restrict__ UzT, const float* __restrict__ UrT,
    const float* __restrict__ UhT, const int* __restrict__ tree,
    float* node_h, float* pz, float* pr, float* pc, float* qa,
    int* done, int* g_rem)
{
  int wid = blockIdx.x*4 + (threadIdx.x>>6);
  int lane = threadIdx.x & 63;
  if (wid >= NN) return;
  const float* w = xw + wid*KW;
  const int*   v = xi + wid*KW;
  const float* Erow = E + (size_t)lane*VC;
  float xev = 0.f;
  for (int k = 0; k < KW; ++k) xev += w[k] * Erow[v[k]];
  fused_body(wid, lane, xev, WzT,WrT,WhT,Wa, bz,br,bh, UzT,UrT,UhT, tree,
             node_h, pz,pr,pc,qa, done, g_rem);
}

__device__ __forceinline__ bool lvl_ready(int c, int lvl, const int* done){
  if (c < NL) return true;
  int e = done[c - NL];
  return (e > 0 && e < lvl);
}

// ------------- K3: single-block cleanup (guaranteed termination backstop) -------------
__global__ void __launch_bounds__(256) k_cleanup(const int* __restrict__ tree,
    const float* __restrict__ qa, const float* __restrict__ pz,
    const float* __restrict__ pr, const float* __restrict__ pc,
    const float* __restrict__ UzT, const float* __restrict__ UrT,
    const float* __restrict__ UhT,
    float* node_h, int* done, int* g_rem)
{
  int rem = *g_rem;
  if (rem <= 0) return;
  __shared__ int cnt_s;
  int w = threadIdx.x >> 6, lane = threadIdx.x & 63;
  int epoch = CLEAN_EPOCH;
  while (rem > 0){
    if (threadIdx.x == 0) cnt_s = 0;
    __syncthreads();
    int my = 0;
    for (int i = w; i < NP; i += 4){
      if (done[i]) continue;
      const int* tr = tree + i*5;
      int c0=tr[0], c1=tr[1], c2=tr[2], c3=tr[3];
      if (!(lvl_ready(c0,epoch,done) && lvl_ready(c1,epoch,done)
         && lvl_ready(c2,epoch,done) && lvl_ready(c3,epoch,done))) continue;
      float chv0 = (c0>=0)? node_h[c0*64+lane] : 0.f;
      float chv1 = (c1>=0)? node_h[c1*64+lane] : 0.f;
      float chv2 = (c2>=0)? node_h[c2*64+lane] : 0.f;
      float chv3 = (c3>=0)? node_h[c3*64+lane] : 0.f;
      float h = gru_compute(lane, c0,c1,c2,c3, chv0,chv1,chv2,chv3,
                            qa[i*64+lane], pz[i*64+lane], pr[i*64+lane], pc[i*64+lane],
                            UzT, UrT, UhT);
      node_h[(size_t)(NL+i)*64+lane] = h;
      if (lane==0) done[i] = epoch;
      ++my;
    }
    if (lane==0 && my) atomicAdd(&cnt_s, my);
    __syncthreads();
    rem -= cnt_s;
    ++epoch;
    __syncthreads();
  }
}

// ---------------- K4a/K4b: max-pool + head ----------------
__global__ void k_max1(const float* __restrict__ node_h, float* __restrict__ partial){
  __shared__ float sm[4][64];
  int lane = threadIdx.x & 63, w = threadIdx.x>>6;
  int base = NL + blockIdx.x*128;
  float m = -1e30f;
  for (int r = w; r < 128; r += 4)
    m = fmaxf(m, node_h[(size_t)(base+r)*64 + lane]);
  sm[w][lane] = m;
  __syncthreads();
  if (w==0){
    m = fmaxf(fmaxf(sm[0][lane],sm[1][lane]), fmaxf(sm[2][lane],sm[3][lane]));
    partial[blockIdx.x*64+lane] = m;
  }
}

__global__ void k_max2(const float* __restrict__ partial, const float* __restrict__ Wout,
                       const float* __restrict__ bout, float* __restrict__ out){
  int lane = threadIdx.x;   // 64 threads = 1 wave
  float m = -1e30f;
  for (int b=0;b<64;++b) m = fmaxf(m, partial[b*64+lane]);
  float s0 = Wout[0*64+lane]*m;
  float s1 = Wout[1*64+lane]*m;
  float s2 = Wout[2*64+lane]*m;
  float s3 = Wout[3*64+lane]*m;
  #pragma unroll
  for (int off=32; off; off>>=1){
    s0 += __shfl_xor(s0, off);
    s1 += __shfl_xor(s1, off);
    s2 += __shfl_xor(s2, off);
    s3 += __shfl_xor(s3, off);
  }
  s0 += bout[0]; s1 += bout[1]; s2 += bout[2]; s3 += bout[3];
  float mx = fmaxf(fmaxf(s0,s1), fmaxf(s2,s3));
  float e0=expf(s0-mx), e1=expf(s1-mx), e2=expf(s2-mx), e3=expf(s3-mx);
  float inv = 1.f/(e0+e1+e2+e3);
  if (lane==0){
    out[0]=e0*inv; out[1]=e1*inv; out[2]=e2*inv; out[3]=e3*inv;
  }
}

__global__ void k_ws_sentinel(float* out, float wsmb){
  if (threadIdx.x < 4) out[threadIdx.x] = wsmb;
}

extern "C" void kernel_launch(void* const* d_in, const int* in_sizes, int n_in,
                              void* d_out, int out_size, void* d_ws, size_t ws_size,
                              hipStream_t stream){
  const float* x_word = (const float*)d_in[0];
  const int*   x_index= (const int*)d_in[1];
  const int*   tree   = (const int*)d_in[2];
  const float* E      = (const float*)d_in[3];
  const float* Wz     = (const float*)d_in[4];
  const float* Uz     = (const float*)d_in[5];
  const float* bz     = (const float*)d_in[6];
  const float* Wr     = (const float*)d_in[7];
  const float* Ur     = (const float*)d_in[8];
  const float* br     = (const float*)d_in[9];
  const float* Wh     = (const float*)d_in[10];
  const float* Uh     = (const float*)d_in[11];
  const float* bh     = (const float*)d_in[12];
  const float* Wa     = (const float*)d_in[13];
  const float* Wout   = (const float*)d_in[14];
  const float* bout   = (const float*)d_in[15];
  float* out = (float*)d_out;

  float* ws = (float*)d_ws;

  // Layout (r11-proven): ET (6,400,000 f) is READ by k_fused, so everything k_fused
  // writes lives in the tail. Only part (4,096 f, written by k_max1) aliases ET.
  // Tail: qa/pz/pr/pc (2,097,152) | nodeh (1,048,576) | WT (24,576) | done (NP) | g_rem.
  const size_t R0_FULL = 6400000;
  const size_t R0_FB   = 4096;               // part only
  const size_t TAIL    = 2097152 + 1048576 + 24576 + NP + 1;
  const size_t FULL_NEED = (R0_FULL + TAIL) * 4;   // ~38.3 MB (ran full in r11)
  const size_t FB_NEED   = (R0_FB   + TAIL) * 4;   // ~12.7 MB

  bool full = (ws_size >= FULL_NEED);
  bool fb   = (!full && ws_size >= FB_NEED);
  if (!full && !fb){
    k_ws_sentinel<<<1, 64, 0, stream>>>(out, (float)(ws_size >> 20));
    return;
  }

  float* ET   = ws;                          // full path only; dead after k_fused
  float* part = ws;                          // aliases ET; written only by k_max1
  size_t r0   = full ? R0_FULL : R0_FB;
  float* qa    = ws + r0;                    // 4 x 524,288
  float* pz    = qa + 524288;
  float* pr    = pz + 524288;
  float* pc    = pr + 524288;
  float* nodeh = pc + 524288;                // 1,048,576 f
  float* WT    = nodeh + 1048576;            // 24,576 f
  int*   done  = (int*)(WT + 24576);         // NP
  int*   g_rem = done + NP;                  // 1
  float* WzT = WT,       *WrT = WT+4096,  *WhT = WT+8192;
  float* UzT = WT+12288, *UrT = WT+16384, *UhT = WT+20480;

  int et_blocks = full ? (VC+63)/64 : 0;     // 1563 or 0
  k_setup<<<et_blocks + 6 + 4096 + NP/256, 256, 0, stream>>>(
      E, ET, Wz, Wr, Wh, Uz, Ur, Uh, WT, nodeh, done, g_rem, et_blocks);
  if (full)
    k_fused<<<NN/4, 256, 0, stream>>>(x_word, x_index, ET, WzT, WrT, WhT, Wa,
                                      bz, br, bh, UzT, UrT, UhT, tree,
                                      nodeh, pz, pr, pc, qa, done, g_rem);
  else
    k_fused_direct<<<NN/4, 256, 0, stream>>>(x_word, x_index, E, WzT, WrT, WhT, Wa,
                                             bz, br, bh, UzT, UrT, UhT, tree,
                                             nodeh, pz, pr, pc, qa, done, g_rem);
  k_cleanup<<<1,  256, 0, stream>>>(tree, qa, pz, pr, pc, UzT, UrT, UhT,
                                    nodeh, done, g_rem);
  k_max1   <<<64, 256, 0, stream>>>(nodeh, part);
  k_max2   <<<1,   64, 0, stream>>>(part, Wout, bout, out);
}